// Round 22
// baseline (2964.487 us; speedup 1.0000x reference)
//
#include <hip/hip_runtime.h>
#include <hip/hip_bf16.h>

// ---------------------------------------------------------------------------
// 4-layer LSTM stack + inference BatchNorm, B=512 T=256 F=128, H=256/128/64/32
//  r22: r20 body (packed uint4 layer-1 U, 8-deep) with ONE change:
//  layer-1 M=2 -> 4 (grid 128). r21 showed layer-1 is L2-BW-bound
//  (16-deep regressed, eff 5.8 TB/s/XCD); M=4 halves per-XCD U traffic
//  (arithmetic intensity 2x) while VALU stays under the BW time.
//  Bit-identical numerics. Layers 2-4 + GEMM unchanged.
// ---------------------------------------------------------------------------

typedef __attribute__((ext_vector_type(4))) float f32x4;
typedef _Float16 half_t;
typedef __attribute__((ext_vector_type(2))) _Float16 half2_t;
typedef __attribute__((ext_vector_type(8))) _Float16 half8;

__device__ __forceinline__ float fsig(float x)  { return 1.f / (1.f + __expf(-x)); }
__device__ __forceinline__ float ftanh(float x) { return 1.f - 2.f / (1.f + __expf(2.f * x)); }

__device__ __forceinline__ float fdot2(half2_t a, half2_t b, float c) {
#if defined(__has_builtin)
#if __has_builtin(__builtin_amdgcn_fdot2)
    return __builtin_amdgcn_fdot2(a, b, c, false);
#else
    return c + (float)a[0] * (float)b[0] + (float)a[1] * (float)b[1];
#endif
#else
    return c + (float)a[0] * (float)b[0] + (float)a[1] * (float)b[1];
#endif
}
__device__ __forceinline__ half2_t h2(unsigned u) { return __builtin_bit_cast(half2_t, u); }

// ---------------------------------------------------------------------------
// prep: W[k][c] fp32 -> fp16 hi/lo, chunked [(k/8)*N4 + c][k%8]
// ---------------------------------------------------------------------------
__global__ void w_split_h(const float* __restrict__ W, half_t* __restrict__ hi,
                          half_t* __restrict__ lo, int K, int N4)
{
    int idx = blockIdx.x * 256 + threadIdx.x;
    if (idx < K * N4) {
        int k = idx / N4, c = idx - k * N4;
        float v = W[idx];
        half_t h = (half_t)v;
        half_t l = (half_t)(v - (float)h);
        size_t o = ((size_t)(k >> 3) * N4 + c) * 8 + (k & 7);
        hi[o] = h; lo[o] = l;
    }
}

// prep: U fp32 -> fp16, chunked [(k/4)*H4 + c][k%4]   (layer 2)
__global__ void u_chunk_h(const float* __restrict__ U, half_t* __restrict__ Ut,
                          int H, int H4)
{
    int idx = blockIdx.x * 256 + threadIdx.x;
    if (idx < H * H4) {
        int k = idx / H4, c = idx - k * H4;
        Ut[((size_t)(k >> 2) * H4 + c) * 4 + (k & 3)] = (half_t)U[idx];
    }
}

// prep: U fp32 -> fp16 PACKED-uint4 (layer 1, G=2/GPG=2): for chunk kc,
// slot s=(g*H+j): {col(g*2H+j) k0k1, k2k3, col(g*2H+H+j) k0k1, k2k3}
__global__ void u_pack4(const float* __restrict__ U, uint4* __restrict__ Ut4, int H)
{
    const int TPB = H * 2, NCH = H / 4, H4 = 4 * H;
    int idx = blockIdx.x * 256 + threadIdx.x;
    if (idx < NCH * TPB) {
        int kc = idx / TPB, s = idx - kc * TPB;
        int g = s / H, j = s - g * H;
        unsigned r[4];
#pragma unroll
        for (int q = 0; q < 2; ++q) {
            int col = g * 2 * H + q * H + j;
#pragma unroll
            for (int p = 0; p < 2; ++p) {
                half2_t hp;
                hp[0] = (half_t)U[(size_t)(4 * kc + 2 * p) * H4 + col];
                hp[1] = (half_t)U[(size_t)(4 * kc + 2 * p + 1) * H4 + col];
                r[q * 2 + p] = __builtin_bit_cast(unsigned, hp);
            }
        }
        Ut4[idx] = make_uint4(r[0], r[1], r[2], r[3]);
    }
}

// prep: U fp32 chunked (layers 3-4, LDS-persistent)
__global__ void u_chunk(const float* __restrict__ U, float* __restrict__ Ut,
                        int H, int H4)
{
    int idx = blockIdx.x * 256 + threadIdx.x;
    if (idx < H * H4) {
        int k = idx / H4, c = idx - k * H4;
        Ut[((size_t)(k >> 2) * H4 + c) * 4 + (k & 3)] = U[idx];
    }
}

// ---------------------------------------------------------------------------
// XW GEMM: 64x64 tile, BK=32, 256 threads. A single fp16, W fp16 hi/lo,
// 2-pass f16 MFMA. C stored fp16.  (r16 body, unchanged)
// ---------------------------------------------------------------------------
template<bool AF32>
__global__ __launch_bounds__(256) void gemm_f16(
    const float* __restrict__ Af, const half_t* __restrict__ Ahp,
    size_t aRowStride,
    const half_t* __restrict__ Whc, const half_t* __restrict__ Wlc,
    const float* __restrict__ bias, half_t* __restrict__ C,
    int K, int N4, int Tc)
{
    __shared__ half_t As[4][64][8], Wh[4][64][8], Wl[4][64][8];

    const int tid  = threadIdx.x;
    const int lane = tid & 63, wave = tid >> 6;
    const int r0 = blockIdx.x * 64, n0 = blockIdx.y * 64;

    const int akt = tid & 3, arow = tid >> 2;
    const int rr = r0 + arow;
    const int bb = rr / Tc, tc2 = rr - bb * Tc;
    const size_t aOff = (size_t)bb * aRowStride + (size_t)tc2 * K + (akt << 3);
    const int wkt = tid >> 6, wcol = tid & 63;
    const size_t wOff = ((size_t)wkt * N4 + n0 + wcol) * 8;

    f32x4 acc[4];
#pragma unroll
    for (int nt = 0; nt < 4; ++nt) acc[nt] = (f32x4){0.f, 0.f, 0.f, 0.f};

    const int frow = (wave << 4) | (lane & 15);
    const int fkb  = lane >> 4;
    const int bcol = lane & 15;

    const int nkt = K >> 5;
    for (int kt = 0; kt < nkt; ++kt) {
        if constexpr (AF32) {
            const float* ap = Af + aOff + (size_t)kt * 32;
            float av[8];
            *(float4*)&av[0] = *(const float4*)(ap);
            *(float4*)&av[4] = *(const float4*)(ap + 4);
            half8 sh;
#pragma unroll
            for (int e = 0; e < 8; ++e) sh[e] = (half_t)av[e];
            *(half8*)&As[akt][arow][0] = sh;
        } else {
            *(uint4*)&As[akt][arow][0] =
                *(const uint4*)(Ahp + aOff + (size_t)kt * 32);
        }
        *(uint4*)&Wh[wkt][wcol][0] = *(const uint4*)(Whc + wOff + (size_t)kt * 4 * N4 * 8);
        *(uint4*)&Wl[wkt][wcol][0] = *(const uint4*)(Wlc + wOff + (size_t)kt * 4 * N4 * 8);
        __syncthreads();

        half8 a = *(const half8*)&As[fkb][frow][0];
#pragma unroll
        for (int nt = 0; nt < 4; ++nt) {
            half8 b_h = *(const half8*)&Wh[fkb][nt * 16 + bcol][0];
            half8 b_l = *(const half8*)&Wl[fkb][nt * 16 + bcol][0];
            acc[nt] = __builtin_amdgcn_mfma_f32_16x16x32_f16(a, b_h, acc[nt], 0, 0, 0);
            acc[nt] = __builtin_amdgcn_mfma_f32_16x16x32_f16(a, b_l, acc[nt], 0, 0, 0);
        }
        __syncthreads();
    }

    // epilogue: C/D layout col = lane&15, row = (lane>>4)*4 + q   [m89-verified]
    const int crow0 = r0 + (wave << 4) + ((lane >> 4) << 2);
#pragma unroll
    for (int nt = 0; nt < 4; ++nt) {
        int col = n0 + nt * 16 + bcol;
        float bs = bias[col];
#pragma unroll
        for (int q = 0; q < 4; ++q)
            C[(size_t)(crow0 + q) * N4 + col] = (half_t)(acc[nt][q] + bs);
    }
}

// ---------------------------------------------------------------------------
// Recurrent kernel, fp16 U/h (layers 1-2). Gate-split.
// PACKED (layer 1): U in uint4-per-thread-per-chunk layout, 8-deep pipeline,
//                   M=4 (grid 128) for 2x arithmetic intensity per U-read.
// else  (layer 2): r19's uint2 layout, 4-deep pipeline, M=2 (grid 256).
// ---------------------------------------------------------------------------
template<int H, int M, int G, bool PACKED>
__global__ __launch_bounds__(H * G) void lstm_rec_h(
    const half_t* __restrict__ XW, const uint2* __restrict__ Uth,
    const uint4* __restrict__ Ut4,
    const float* __restrict__ bn_g, const float* __restrict__ bn_b,
    const float* __restrict__ bn_m, const float* __restrict__ bn_v,
    half_t* __restrict__ outH, size_t oRowStride,
    float* __restrict__ h_ws, float* __restrict__ c_ws, int t0, int Tc)
{
    constexpr int TPB = H * G;
    constexpr int GPG = 4 / G;
    constexpr int NCH = H / 4;
    constexpr int H4  = 4 * H;
    static_assert(!PACKED || (G == 2 && NCH % 8 == 0), "");

    const int tid = threadIdx.x;
    const int j   = tid & (H - 1);
    const int g   = tid / H;
    const int b0  = blockIdx.x * M;
    const int cbase = g * GPG * H + j;

    __shared__ unsigned hsmh[M][H / 2];        // packed half2
    __shared__ float zx[G - 1][M][GPG][H];

    float scale = 0.f, shift = 0.f, cst[M];
    if (g == 0) {
        scale = bn_g[j] * rsqrtf(bn_v[j] + 1e-3f);
        shift = bn_b[j] - bn_m[j] * scale;
        if (t0 == 0) {
#pragma unroll
            for (int i = 0; i < M; ++i) cst[i] = 0.f;
        } else {
#pragma unroll
            for (int i = 0; i < M; ++i) cst[i] = c_ws[(size_t)(b0 + i) * H + j];
        }
    }
    if (t0 == 0) {
        for (int c = tid; c < M * H / 2; c += TPB) ((unsigned*)hsmh)[c] = 0u;
    } else {
        for (int c = tid; c < M * H; c += TPB) {
            int r = c / H, jj = c - r * H;
            ((half_t*)hsmh)[(size_t)r * H + jj] = (half_t)h_ws[(size_t)(b0 + r) * H + jj];
        }
    }
    __syncthreads();

    for (int tl = 0; tl < Tc; ++tl) {
        float xwv[M][GPG];
#pragma unroll
        for (int i = 0; i < M; ++i) {
            const half_t* xp = XW + ((size_t)(b0 + i) * Tc + tl) * H4 + cbase;
#pragma unroll
            for (int q = 0; q < GPG; ++q) xwv[i][q] = (float)xp[(size_t)q * H];
        }

        float zp[M][GPG];
#pragma unroll
        for (int i = 0; i < M; ++i)
#pragma unroll
            for (int q = 0; q < GPG; ++q) zp[i][q] = 0.f;

        if constexpr (PACKED) {
            uint4 buf[8];
            auto loadC = [&](int s, int kc) {
                if (kc >= NCH) kc -= NCH;      // harmless tail wrap
                buf[s] = Ut4[(size_t)kc * TPB + tid];
            };
            auto fmaC = [&](int s, int kc) {
#pragma unroll
                for (int i = 0; i < M; ++i) {
                    uint2 hv = *(const uint2*)&hsmh[i][kc * 2];
                    half2_t ha = h2(hv.x);
                    half2_t hb = h2(hv.y);
                    zp[i][0] = fdot2(ha, h2(buf[s].x), zp[i][0]);
                    zp[i][0] = fdot2(hb, h2(buf[s].y), zp[i][0]);
                    zp[i][1] = fdot2(ha, h2(buf[s].z), zp[i][1]);
                    zp[i][1] = fdot2(hb, h2(buf[s].w), zp[i][1]);
                }
            };
            loadC(0, 0); loadC(1, 1); loadC(2, 2); loadC(3, 3);
            loadC(4, 4); loadC(5, 5); loadC(6, 6);
            for (int kc = 0; kc < NCH; kc += 8) {
                loadC(7, kc + 7);  fmaC(0, kc);
                loadC(0, kc + 8);  fmaC(1, kc + 1);
                loadC(1, kc + 9);  fmaC(2, kc + 2);
                loadC(2, kc + 10); fmaC(3, kc + 3);
                loadC(3, kc + 11); fmaC(4, kc + 4);
                loadC(4, kc + 12); fmaC(5, kc + 5);
                loadC(5, kc + 13); fmaC(6, kc + 6);
                loadC(6, kc + 14); fmaC(7, kc + 7);
            }
        } else {
            uint2 buf[4][GPG];
            auto loadC = [&](int s, int kc) {
                if (kc >= NCH) kc -= NCH;      // harmless tail wrap
                const uint2* p = Uth + (size_t)kc * H4 + cbase;
#pragma unroll
                for (int q = 0; q < GPG; ++q) buf[s][q] = p[(size_t)q * H];
            };
            auto fmaC = [&](int s, int kc) {
#pragma unroll
                for (int i = 0; i < M; ++i) {
                    uint2 hv = *(const uint2*)&hsmh[i][kc * 2];
                    half2_t ha = h2(hv.x);
                    half2_t hb = h2(hv.y);
#pragma unroll
                    for (int q = 0; q < GPG; ++q) {
                        half2_t ua = h2(buf[s][q].x);
                        half2_t ub = h2(buf[s][q].y);
                        zp[i][q] = fdot2(ha, ua, zp[i][q]);
                        zp[i][q] = fdot2(hb, ub, zp[i][q]);
                    }
                }
            };
            loadC(0, 0); loadC(1, 1); loadC(2, 2);
            for (int kc = 0; kc < NCH; kc += 4) {
                loadC(3, kc + 3); fmaC(0, kc);
                loadC(0, kc + 4); fmaC(1, kc + 1);
                loadC(1, kc + 5); fmaC(2, kc + 2);
                loadC(2, kc + 6); fmaC(3, kc + 3);
            }
        }

#pragma unroll
        for (int i = 0; i < M; ++i)
#pragma unroll
            for (int q = 0; q < GPG; ++q) zp[i][q] += xwv[i][q];

        if (g > 0) {
#pragma unroll
            for (int i = 0; i < M; ++i)
#pragma unroll
                for (int q = 0; q < GPG; ++q) zx[g - 1][i][q][j] = zp[i][q];
        }
        __syncthreads();

        if (g == 0) {
#pragma unroll
            for (int i = 0; i < M; ++i) {
                float zg[4];
#pragma unroll
                for (int gt = 0; gt < 4; ++gt) {
                    int grp = gt / GPG, q = gt - grp * GPG;
                    zg[gt] = (grp == 0) ? zp[i][q] : zx[grp - 1][i][q][j];
                }
                float ig = fsig(zg[0]);
                float fg = fsig(zg[1]);
                float gg = ftanh(zg[2]);
                float og = fsig(zg[3]);
                cst[i] = fg * cst[i] + ig * gg;
                float hv = og * ftanh(cst[i]);
                ((half_t*)hsmh)[(size_t)i * H + j] = (half_t)hv;
                float v = hv * scale + shift;
                size_t o = (size_t)(b0 + i) * oRowStride + (size_t)tl * H + j;
                outH[o] = (half_t)v;
            }
        }
        __syncthreads();
    }

    if (g == 0 && t0 + Tc < 256) {
#pragma unroll
        for (int i = 0; i < M; ++i) {
            size_t r = (size_t)(b0 + i);
            h_ws[r * H + j] = (float)((half_t*)hsmh)[(size_t)i * H + j];
            c_ws[r * H + j] = cst[i];
        }
    }
}

// ---------------------------------------------------------------------------
// Recurrent kernel, fp32 + LDS-persistent U (layers 3-4). XW fp16. M=2.
// ---------------------------------------------------------------------------
template<int H, int M, int G, bool LAST>
__global__ __launch_bounds__(H * G) void lstm_rec32(
    const half_t* __restrict__ XW, const float* __restrict__ Ut,
    const float* __restrict__ bn_g, const float* __restrict__ bn_b,
    const float* __restrict__ bn_m, const float* __restrict__ bn_v,
    half_t* __restrict__ outH, float* __restrict__ outF, size_t oRowStride,
    float* __restrict__ h_ws, float* __restrict__ c_ws, int t0, int Tc)
{
    constexpr int TPB = H * G;
    constexpr int GPG = 4 / G;
    constexpr int NCH = H / 4;
    constexpr int H4  = 4 * H;

    const int tid = threadIdx.x;
    const int j   = tid & (H - 1);
    const int g   = tid / H;
    const int b0  = blockIdx.x * M;
    const int cbase = g * GPG * H + j;

    __shared__ float hsm[M][H];
    __shared__ float zx[G - 1][M][GPG][H];
    __shared__ float Us[4 * H * H];

    for (int i = tid * 4; i < 4 * H * H; i += TPB * 4)
        *(float4*)&Us[i] = *(const float4*)&Ut[i];

    float scale = 0.f, shift = 0.f, cst[M];
    if (g == 0) {
        scale = bn_g[j] * rsqrtf(bn_v[j] + 1e-3f);
        shift = bn_b[j] - bn_m[j] * scale;
        if (t0 == 0) {
#pragma unroll
            for (int i = 0; i < M; ++i) cst[i] = 0.f;
        } else {
#pragma unroll
            for (int i = 0; i < M; ++i) cst[i] = c_ws[(size_t)(b0 + i) * H + j];
        }
    }
    if (t0 == 0) {
        for (int c = tid; c < M * H; c += TPB) ((float*)hsm)[c] = 0.f;
    } else {
        for (int c = tid; c < M * H; c += TPB) {
            int r = c / H, jj = c - r * H;
            ((float*)hsm)[c] = h_ws[(size_t)(b0 + r) * H + jj];
        }
    }
    __syncthreads();

    for (int tl = 0; tl < Tc; ++tl) {
        float xwv[M][GPG];
#pragma unroll
        for (int i = 0; i < M; ++i) {
            const half_t* xp = XW + ((size_t)(b0 + i) * Tc + tl) * H4 + cbase;
#pragma unroll
            for (int q = 0; q < GPG; ++q) xwv[i][q] = (float)xp[(size_t)q * H];
        }

        float zp[M][GPG];
#pragma unroll
        for (int i = 0; i < M; ++i)
#pragma unroll
            for (int q = 0; q < GPG; ++q) zp[i][q] = 0.f;

#pragma unroll
        for (int kc = 0; kc < NCH; ++kc) {
            float4 ub[GPG];
#pragma unroll
            for (int q = 0; q < GPG; ++q)
                ub[q] = *(const float4*)&Us[((size_t)kc * H4 + cbase + q * H) * 4];
#pragma unroll
            for (int i = 0; i < M; ++i) {
                const float4 h4 = *(const float4*)&hsm[i][kc * 4];
#pragma unroll
                for (int q = 0; q < GPG; ++q)
                    zp[i][q] += h4.x * ub[q].x + h4.y * ub[q].y
                              + h4.z * ub[q].z + h4.w * ub[q].w;
            }
        }

#pragma unroll
        for (int i = 0; i < M; ++i)
#pragma unroll
            for (int q = 0; q < GPG; ++q) zp[i][q] += xwv[i][q];

        if (g > 0) {
#pragma unroll
            for (int i = 0; i < M; ++i)
#pragma unroll
                for (int q = 0; q < GPG; ++q) zx[g - 1][i][q][j] = zp[i][q];
        }
        __syncthreads();

        if (g == 0) {
            const int t = t0 + tl;
#pragma unroll
            for (int i = 0; i < M; ++i) {
                float zg[4];
#pragma unroll
                for (int gt = 0; gt < 4; ++gt) {
                    int grp = gt / GPG, q = gt - grp * GPG;
                    zg[gt] = (grp == 0) ? zp[i][q] : zx[grp - 1][i][q][j];
                }
                float ig = fsig(zg[0]);
                float fg = fsig(zg[1]);
                float gg = ftanh(zg[2]);
                float og = fsig(zg[3]);
                cst[i] = fg * cst[i] + ig * gg;
                float hv = og * ftanh(cst[i]);
                hsm[i][j] = hv;
                float v = hv * scale + shift;
                size_t r = (size_t)(b0 + i);
                if constexpr (!LAST) {
                    size_t o = r * oRowStride + (size_t)tl * H + j;
                    outH[o] = (half_t)v;
                } else {
                    if (t == 255) outF[r * H + j] = v;
                }
            }
        }
        __syncthreads();
    }

    if (g == 0 && t0 + Tc < 256) {
#pragma unroll
        for (int i = 0; i < M; ++i) {
            size_t r = (size_t)(b0 + i);
            h_ws[r * H + j] = hsm[i][j];
            c_ws[r * H + j] = cst[i];
        }
    }
}

// ---------------------------------------------------------------------------
extern "C" void kernel_launch(void* const* d_in, const int* in_sizes, int n_in,
                              void* d_out, int out_size, void* d_ws, size_t ws_size,
                              hipStream_t stream)
{
    const float* state = (const float*)d_in[0];
    const float *W[4], *U[4], *bi[4], *g[4], *be[4], *mm[4], *vv[4];
    for (int l = 0; l < 4; ++l) {
        W[l]  = (const float*)d_in[1 + 7 * l + 0];
        U[l]  = (const float*)d_in[1 + 7 * l + 1];
        bi[l] = (const float*)d_in[1 + 7 * l + 2];
        g[l]  = (const float*)d_in[1 + 7 * l + 3];
        be[l] = (const float*)d_in[1 + 7 * l + 4];
        mm[l] = (const float*)d_in[1 + 7 * l + 5];
        vv[l] = (const float*)d_in[1 + 7 * l + 6];
    }
    const int HS[4]  = {256, 128, 64, 32};
    const int FIN[4] = {128, 256, 128, 64};

    // ---- fixed-buffer byte sizes ----------------------------------------
    size_t wB[4], uthB[2], utB[2], hB[4];
    size_t fixed = 0;
    for (int l = 0; l < 4; ++l) { wB[l] = (size_t)FIN[l] * 4 * HS[l] * 2; fixed += 2 * ((wB[l] + 15) & ~15ull); }
    for (int l = 0; l < 2; ++l) { uthB[l] = (size_t)4 * HS[l] * HS[l] * 2; fixed += (uthB[l] + 15) & ~15ull; }
    fixed += (uthB[0] + 15) & ~15ull;   // layer-1 packed copy (same byte count)
    for (int l = 0; l < 2; ++l) { utB[l] = (size_t)4 * HS[l + 2] * HS[l + 2] * 4; fixed += (utB[l] + 15) & ~15ull; }
    for (int l = 0; l < 4; ++l) { hB[l] = (size_t)512 * HS[l] * 4; fixed += 2 * ((hB[l] + 15) & ~15ull); }
    fixed += 1024;  // alignment slack

    // fp16 xw + fp16 single activations
    auto xwBytes  = [&](size_t tc) { return (size_t)512 * tc * 1024 * 2; };
    auto actBytes = [&](size_t t)  { return (size_t)512 * t * (256 + 128 + 64) * 2; };

    int Tc = 256; bool fullAct = true;
    while (Tc > 8 && fixed + xwBytes(Tc) + actBytes(256) > ws_size) Tc >>= 1;
    if (fixed + xwBytes(Tc) + actBytes(256) > ws_size) {
        fullAct = false; Tc = 32;
        while (Tc > 1 && fixed + xwBytes(Tc) + actBytes(Tc) > ws_size) Tc >>= 1;
    }
    int nc = 256 / Tc;
    size_t Tact = fullAct ? 256 : (size_t)Tc;

    // ---- allocate --------------------------------------------------------
    size_t off = 0;
    auto alloc = [&](size_t bytes) -> char* {
        char* p = (char*)d_ws + off;
        off = (off + bytes + 15) & ~15ull;
        return p;
    };
    half_t* xw = (half_t*)alloc(xwBytes(Tc));
    half_t* act[4];
    act[0] = nullptr;
    for (int l = 1; l < 4; ++l)
        act[l] = (half_t*)alloc((size_t)512 * Tact * FIN[l] * 2);
    float *hb[4], *cb[4];
    for (int l = 0; l < 4; ++l) { hb[l] = (float*)alloc(hB[l]); cb[l] = (float*)alloc(hB[l]); }
    half_t* uth1 = (half_t*)alloc(uthB[1]);          // layer-2 uint2 layout
    uint4*  ut4  = (uint4*)alloc(uthB[0]);           // layer-1 packed layout
    float* ut[2];
    for (int l = 0; l < 2; ++l) ut[l] = (float*)alloc(utB[l]);
    half_t *whi[4], *wlo[4];
    for (int l = 0; l < 4; ++l) { whi[l] = (half_t*)alloc(wB[l]); wlo[l] = (half_t*)alloc(wB[l]); }

    // ---- one-time prep ---------------------------------------------------
    for (int l = 0; l < 4; ++l) {
        int n = FIN[l] * 4 * HS[l];
        w_split_h<<<dim3((n + 255) / 256), dim3(256), 0, stream>>>(W[l], whi[l], wlo[l], FIN[l], 4 * HS[l]);
    }
    {   // layer-1 packed U
        int n = (HS[0] / 4) * (HS[0] * 2);           // NCH * TPB = 32768
        u_pack4<<<dim3((n + 255) / 256), dim3(256), 0, stream>>>(U[0], ut4, HS[0]);
    }
    {   // layer-2 uint2 U
        int n = HS[1] * 4 * HS[1];
        u_chunk_h<<<dim3((n + 255) / 256), dim3(256), 0, stream>>>(U[1], uth1, HS[1], 4 * HS[1]);
    }
    for (int l = 0; l < 2; ++l) {
        int n = HS[l + 2] * 4 * HS[l + 2];
        u_chunk<<<dim3((n + 255) / 256), dim3(256), 0, stream>>>(U[l + 2], ut[l], HS[l + 2], 4 * HS[l + 2]);
    }

    // ---- time-chunk-interleaved layer sweep -----------------------------
    for (int c = 0; c < nc; ++c) {
        int t0 = c * Tc;
        for (int l = 0; l < 4; ++l) {
            int K = FIN[l], N4 = 4 * HS[l];
            dim3 gg((512 * Tc) / 64, N4 / 64);

            if (l == 0) {
                const float* Abase = state + (size_t)t0 * 128;
                gemm_f16<true><<<gg, dim3(256), 0, stream>>>(
                    Abase, nullptr, (size_t)256 * 128,
                    whi[0], wlo[0], bi[0], xw, K, N4, Tc);
            } else {
                size_t aOff = fullAct ? (size_t)t0 * K : 0;
                size_t aStride = fullAct ? (size_t)256 * K : (size_t)Tc * K;
                gemm_f16<false><<<gg, dim3(256), 0, stream>>>(
                    nullptr, act[l] + aOff, aStride,
                    whi[l], wlo[l], bi[l], xw, K, N4, Tc);
            }

            half_t* oH = nullptr;
            size_t oStride = 0;
            if (l < 3) {
                size_t oOff = fullAct ? (size_t)t0 * HS[l] : 0;
                oStride = fullAct ? (size_t)256 * HS[l] : (size_t)Tc * HS[l];
                oH = act[l + 1] + oOff;
            }

            if (l == 0)
                lstm_rec_h<256, 4, 2, true><<<dim3(128), dim3(512), 0, stream>>>(
                    xw, nullptr, ut4, g[0], be[0], mm[0], vv[0],
                    oH, oStride, hb[0], cb[0], t0, Tc);
            else if (l == 1)
                lstm_rec_h<128, 2, 4, false><<<dim3(256), dim3(512), 0, stream>>>(
                    xw, (const uint2*)uth1, nullptr, g[1], be[1], mm[1], vv[1],
                    oH, oStride, hb[1], cb[1], t0, Tc);
            else if (l == 2)
                lstm_rec32<64, 2, 4, false><<<dim3(256), dim3(256), 0, stream>>>(
                    xw, ut[0], g[2], be[2], mm[2], vv[2],
                    oH, nullptr, oStride, hb[2], cb[2], t0, Tc);
            else
                lstm_rec32<32, 2, 4, true><<<dim3(256), dim3(128), 0, stream>>>(
                    xw, ut[1], g[3], be[3], mm[3], vv[3],
                    nullptr, (float*)d_out, 0, hb[3], cb[3], t0, Tc);
        }
    }
}

// Round 23
// 2408.212 us; speedup vs baseline: 1.2310x; 1.2310x over previous
//
#include <hip/hip_runtime.h>
#include <hip/hip_bf16.h>

// ---------------------------------------------------------------------------
// 4-layer LSTM stack + inference BatchNorm, B=512 T=256 F=128, H=256/128/64/32
//  r23: layer-1 reverted to r20 optimum (M=2, packed uint4, 8-deep; 701us,
//  measured best of M-sweep 1139/1113/701/727/943). NEW: layer-2 U packed
//  (2 k-chunks of the thread's column per uint4, 8-deep) — same mechanism
//  that gave layer-1 -37%. Bit-identical numerics. GEMM/layers3-4 unchanged.
// ---------------------------------------------------------------------------

typedef __attribute__((ext_vector_type(4))) float f32x4;
typedef _Float16 half_t;
typedef __attribute__((ext_vector_type(2))) _Float16 half2_t;
typedef __attribute__((ext_vector_type(8))) _Float16 half8;

__device__ __forceinline__ float fsig(float x)  { return 1.f / (1.f + __expf(-x)); }
__device__ __forceinline__ float ftanh(float x) { return 1.f - 2.f / (1.f + __expf(2.f * x)); }

__device__ __forceinline__ float fdot2(half2_t a, half2_t b, float c) {
#if defined(__has_builtin)
#if __has_builtin(__builtin_amdgcn_fdot2)
    return __builtin_amdgcn_fdot2(a, b, c, false);
#else
    return c + (float)a[0] * (float)b[0] + (float)a[1] * (float)b[1];
#endif
#else
    return c + (float)a[0] * (float)b[0] + (float)a[1] * (float)b[1];
#endif
}
__device__ __forceinline__ half2_t h2(unsigned u) { return __builtin_bit_cast(half2_t, u); }

// ---------------------------------------------------------------------------
// prep: W[k][c] fp32 -> fp16 hi/lo, chunked [(k/8)*N4 + c][k%8]
// ---------------------------------------------------------------------------
__global__ void w_split_h(const float* __restrict__ W, half_t* __restrict__ hi,
                          half_t* __restrict__ lo, int K, int N4)
{
    int idx = blockIdx.x * 256 + threadIdx.x;
    if (idx < K * N4) {
        int k = idx / N4, c = idx - k * N4;
        float v = W[idx];
        half_t h = (half_t)v;
        half_t l = (half_t)(v - (float)h);
        size_t o = ((size_t)(k >> 3) * N4 + c) * 8 + (k & 7);
        hi[o] = h; lo[o] = l;
    }
}

// prep: U fp32 -> fp16 PACKED-uint4 (layer 1, G=2/GPG=2): for chunk kc,
// slot s=(g*H+j): {col(g*2H+j) k0k1, k2k3, col(g*2H+H+j) k0k1, k2k3}
__global__ void u_pack4(const float* __restrict__ U, uint4* __restrict__ Ut4, int H)
{
    const int TPB = H * 2, NCH = H / 4, H4 = 4 * H;
    int idx = blockIdx.x * 256 + threadIdx.x;
    if (idx < NCH * TPB) {
        int kc = idx / TPB, s = idx - kc * TPB;
        int g = s / H, j = s - g * H;
        unsigned r[4];
#pragma unroll
        for (int q = 0; q < 2; ++q) {
            int col = g * 2 * H + q * H + j;
#pragma unroll
            for (int p = 0; p < 2; ++p) {
                half2_t hp;
                hp[0] = (half_t)U[(size_t)(4 * kc + 2 * p) * H4 + col];
                hp[1] = (half_t)U[(size_t)(4 * kc + 2 * p + 1) * H4 + col];
                r[q * 2 + p] = __builtin_bit_cast(unsigned, hp);
            }
        }
        Ut4[idx] = make_uint4(r[0], r[1], r[2], r[3]);
    }
}

// prep: U fp32 -> fp16 PACKED-uint4 (layer 2, G=4/GPG=1): for chunk-pair kc2,
// slot s = col (cbase==tid): {col k0k1, k2k3, k4k5, k6k7} (8 consecutive k)
__global__ void u_pack8(const float* __restrict__ U, uint4* __restrict__ Ut4, int H)
{
    const int TPB = H * 4, NC2 = H / 8, H4 = 4 * H;
    int idx = blockIdx.x * 256 + threadIdx.x;
    if (idx < NC2 * TPB) {
        int kc2 = idx / TPB, col = idx - kc2 * TPB;
        unsigned r[4];
#pragma unroll
        for (int p = 0; p < 4; ++p) {
            half2_t hp;
            hp[0] = (half_t)U[(size_t)(8 * kc2 + 2 * p) * H4 + col];
            hp[1] = (half_t)U[(size_t)(8 * kc2 + 2 * p + 1) * H4 + col];
            r[p] = __builtin_bit_cast(unsigned, hp);
        }
        Ut4[idx] = make_uint4(r[0], r[1], r[2], r[3]);
    }
}

// prep: U fp32 chunked (layers 3-4, LDS-persistent)
__global__ void u_chunk(const float* __restrict__ U, float* __restrict__ Ut,
                        int H, int H4)
{
    int idx = blockIdx.x * 256 + threadIdx.x;
    if (idx < H * H4) {
        int k = idx / H4, c = idx - k * H4;
        Ut[((size_t)(k >> 2) * H4 + c) * 4 + (k & 3)] = U[idx];
    }
}

// ---------------------------------------------------------------------------
// XW GEMM: 64x64 tile, BK=32, 256 threads. A single fp16, W fp16 hi/lo,
// 2-pass f16 MFMA. C stored fp16.  (r16 body, unchanged)
// ---------------------------------------------------------------------------
template<bool AF32>
__global__ __launch_bounds__(256) void gemm_f16(
    const float* __restrict__ Af, const half_t* __restrict__ Ahp,
    size_t aRowStride,
    const half_t* __restrict__ Whc, const half_t* __restrict__ Wlc,
    const float* __restrict__ bias, half_t* __restrict__ C,
    int K, int N4, int Tc)
{
    __shared__ half_t As[4][64][8], Wh[4][64][8], Wl[4][64][8];

    const int tid  = threadIdx.x;
    const int lane = tid & 63, wave = tid >> 6;
    const int r0 = blockIdx.x * 64, n0 = blockIdx.y * 64;

    const int akt = tid & 3, arow = tid >> 2;
    const int rr = r0 + arow;
    const int bb = rr / Tc, tc2 = rr - bb * Tc;
    const size_t aOff = (size_t)bb * aRowStride + (size_t)tc2 * K + (akt << 3);
    const int wkt = tid >> 6, wcol = tid & 63;
    const size_t wOff = ((size_t)wkt * N4 + n0 + wcol) * 8;

    f32x4 acc[4];
#pragma unroll
    for (int nt = 0; nt < 4; ++nt) acc[nt] = (f32x4){0.f, 0.f, 0.f, 0.f};

    const int frow = (wave << 4) | (lane & 15);
    const int fkb  = lane >> 4;
    const int bcol = lane & 15;

    const int nkt = K >> 5;
    for (int kt = 0; kt < nkt; ++kt) {
        if constexpr (AF32) {
            const float* ap = Af + aOff + (size_t)kt * 32;
            float av[8];
            *(float4*)&av[0] = *(const float4*)(ap);
            *(float4*)&av[4] = *(const float4*)(ap + 4);
            half8 sh;
#pragma unroll
            for (int e = 0; e < 8; ++e) sh[e] = (half_t)av[e];
            *(half8*)&As[akt][arow][0] = sh;
        } else {
            *(uint4*)&As[akt][arow][0] =
                *(const uint4*)(Ahp + aOff + (size_t)kt * 32);
        }
        *(uint4*)&Wh[wkt][wcol][0] = *(const uint4*)(Whc + wOff + (size_t)kt * 4 * N4 * 8);
        *(uint4*)&Wl[wkt][wcol][0] = *(const uint4*)(Wlc + wOff + (size_t)kt * 4 * N4 * 8);
        __syncthreads();

        half8 a = *(const half8*)&As[fkb][frow][0];
#pragma unroll
        for (int nt = 0; nt < 4; ++nt) {
            half8 b_h = *(const half8*)&Wh[fkb][nt * 16 + bcol][0];
            half8 b_l = *(const half8*)&Wl[fkb][nt * 16 + bcol][0];
            acc[nt] = __builtin_amdgcn_mfma_f32_16x16x32_f16(a, b_h, acc[nt], 0, 0, 0);
            acc[nt] = __builtin_amdgcn_mfma_f32_16x16x32_f16(a, b_l, acc[nt], 0, 0, 0);
        }
        __syncthreads();
    }

    // epilogue: C/D layout col = lane&15, row = (lane>>4)*4 + q   [m89-verified]
    const int crow0 = r0 + (wave << 4) + ((lane >> 4) << 2);
#pragma unroll
    for (int nt = 0; nt < 4; ++nt) {
        int col = n0 + nt * 16 + bcol;
        float bs = bias[col];
#pragma unroll
        for (int q = 0; q < 4; ++q)
            C[(size_t)(crow0 + q) * N4 + col] = (half_t)(acc[nt][q] + bs);
    }
}

// ---------------------------------------------------------------------------
// Recurrent kernel, fp16 U/h (layers 1-2). Gate-split, M=2, 256 blocks.
// PK=1 (layer 1, G=2): uint4 = 2 cols x 4k per chunk, 8-deep pipeline.
// PK=2 (layer 2, G=4): uint4 = 1 col x 8k per chunk-pair, 8-deep pipeline.
// ---------------------------------------------------------------------------
template<int H, int M, int G, int PK>
__global__ __launch_bounds__(H * G) void lstm_rec_h(
    const half_t* __restrict__ XW, const uint4* __restrict__ Ut4,
    const float* __restrict__ bn_g, const float* __restrict__ bn_b,
    const float* __restrict__ bn_m, const float* __restrict__ bn_v,
    half_t* __restrict__ outH, size_t oRowStride,
    float* __restrict__ h_ws, float* __restrict__ c_ws, int t0, int Tc)
{
    constexpr int TPB = H * G;
    constexpr int GPG = 4 / G;
    constexpr int NCH = H / 4;
    constexpr int NC2 = H / 8;
    constexpr int H4  = 4 * H;
    static_assert((PK == 1 && G == 2 && NCH % 8 == 0) ||
                  (PK == 2 && G == 4 && NC2 % 8 == 0), "");

    const int tid = threadIdx.x;
    const int j   = tid & (H - 1);
    const int g   = tid / H;
    const int b0  = blockIdx.x * M;
    const int cbase = g * GPG * H + j;

    __shared__ alignas(16) unsigned hsmh[M][H / 2];   // packed half2
    __shared__ float zx[G - 1][M][GPG][H];

    float scale = 0.f, shift = 0.f, cst[M];
    if (g == 0) {
        scale = bn_g[j] * rsqrtf(bn_v[j] + 1e-3f);
        shift = bn_b[j] - bn_m[j] * scale;
        if (t0 == 0) {
#pragma unroll
            for (int i = 0; i < M; ++i) cst[i] = 0.f;
        } else {
#pragma unroll
            for (int i = 0; i < M; ++i) cst[i] = c_ws[(size_t)(b0 + i) * H + j];
        }
    }
    if (t0 == 0) {
        for (int c = tid; c < M * H / 2; c += TPB) ((unsigned*)hsmh)[c] = 0u;
    } else {
        for (int c = tid; c < M * H; c += TPB) {
            int r = c / H, jj = c - r * H;
            ((half_t*)hsmh)[(size_t)r * H + jj] = (half_t)h_ws[(size_t)(b0 + r) * H + jj];
        }
    }
    __syncthreads();

    for (int tl = 0; tl < Tc; ++tl) {
        float xwv[M][GPG];
#pragma unroll
        for (int i = 0; i < M; ++i) {
            const half_t* xp = XW + ((size_t)(b0 + i) * Tc + tl) * H4 + cbase;
#pragma unroll
            for (int q = 0; q < GPG; ++q) xwv[i][q] = (float)xp[(size_t)q * H];
        }

        float zp[M][GPG];
#pragma unroll
        for (int i = 0; i < M; ++i)
#pragma unroll
            for (int q = 0; q < GPG; ++q) zp[i][q] = 0.f;

        if constexpr (PK == 1) {
            uint4 buf[8];
            auto loadC = [&](int s, int kc) {
                if (kc >= NCH) kc -= NCH;      // harmless tail wrap
                buf[s] = Ut4[(size_t)kc * TPB + tid];
            };
            auto fmaC = [&](int s, int kc) {
#pragma unroll
                for (int i = 0; i < M; ++i) {
                    uint2 hv = *(const uint2*)&hsmh[i][kc * 2];
                    half2_t ha = h2(hv.x);
                    half2_t hb = h2(hv.y);
                    zp[i][0] = fdot2(ha, h2(buf[s].x), zp[i][0]);
                    zp[i][0] = fdot2(hb, h2(buf[s].y), zp[i][0]);
                    zp[i][1] = fdot2(ha, h2(buf[s].z), zp[i][1]);
                    zp[i][1] = fdot2(hb, h2(buf[s].w), zp[i][1]);
                }
            };
            loadC(0, 0); loadC(1, 1); loadC(2, 2); loadC(3, 3);
            loadC(4, 4); loadC(5, 5); loadC(6, 6);
            for (int kc = 0; kc < NCH; kc += 8) {
                loadC(7, kc + 7);  fmaC(0, kc);
                loadC(0, kc + 8);  fmaC(1, kc + 1);
                loadC(1, kc + 9);  fmaC(2, kc + 2);
                loadC(2, kc + 10); fmaC(3, kc + 3);
                loadC(3, kc + 11); fmaC(4, kc + 4);
                loadC(4, kc + 12); fmaC(5, kc + 5);
                loadC(5, kc + 13); fmaC(6, kc + 6);
                loadC(6, kc + 14); fmaC(7, kc + 7);
            }
        } else {
            // PK == 2: one column, 8 consecutive k per uint4 (chunk pair)
            uint4 buf[8];
            auto loadC = [&](int s, int kc2) {
                if (kc2 >= NC2) kc2 -= NC2;    // harmless tail wrap
                buf[s] = Ut4[(size_t)kc2 * TPB + tid];
            };
            auto fmaC = [&](int s, int kc2) {
#pragma unroll
                for (int i = 0; i < M; ++i) {
                    uint4 hv = *(const uint4*)&hsmh[i][kc2 * 4];
                    zp[i][0] = fdot2(h2(hv.x), h2(buf[s].x), zp[i][0]);
                    zp[i][0] = fdot2(h2(hv.y), h2(buf[s].y), zp[i][0]);
                    zp[i][0] = fdot2(h2(hv.z), h2(buf[s].z), zp[i][0]);
                    zp[i][0] = fdot2(h2(hv.w), h2(buf[s].w), zp[i][0]);
                }
            };
            loadC(0, 0); loadC(1, 1); loadC(2, 2); loadC(3, 3);
            loadC(4, 4); loadC(5, 5); loadC(6, 6);
            for (int kc2 = 0; kc2 < NC2; kc2 += 8) {
                loadC(7, kc2 + 7);  fmaC(0, kc2);
                loadC(0, kc2 + 8);  fmaC(1, kc2 + 1);
                loadC(1, kc2 + 9);  fmaC(2, kc2 + 2);
                loadC(2, kc2 + 10); fmaC(3, kc2 + 3);
                loadC(3, kc2 + 11); fmaC(4, kc2 + 4);
                loadC(4, kc2 + 12); fmaC(5, kc2 + 5);
                loadC(5, kc2 + 13); fmaC(6, kc2 + 6);
                loadC(6, kc2 + 14); fmaC(7, kc2 + 7);
            }
        }

#pragma unroll
        for (int i = 0; i < M; ++i)
#pragma unroll
            for (int q = 0; q < GPG; ++q) zp[i][q] += xwv[i][q];

        if (g > 0) {
#pragma unroll
            for (int i = 0; i < M; ++i)
#pragma unroll
                for (int q = 0; q < GPG; ++q) zx[g - 1][i][q][j] = zp[i][q];
        }
        __syncthreads();

        if (g == 0) {
#pragma unroll
            for (int i = 0; i < M; ++i) {
                float zg[4];
#pragma unroll
                for (int gt = 0; gt < 4; ++gt) {
                    int grp = gt / GPG, q = gt - grp * GPG;
                    zg[gt] = (grp == 0) ? zp[i][q] : zx[grp - 1][i][q][j];
                }
                float ig = fsig(zg[0]);
                float fg = fsig(zg[1]);
                float gg = ftanh(zg[2]);
                float og = fsig(zg[3]);
                cst[i] = fg * cst[i] + ig * gg;
                float hv = og * ftanh(cst[i]);
                ((half_t*)hsmh)[(size_t)i * H + j] = (half_t)hv;
                float v = hv * scale + shift;
                size_t o = (size_t)(b0 + i) * oRowStride + (size_t)tl * H + j;
                outH[o] = (half_t)v;
            }
        }
        __syncthreads();
    }

    if (g == 0 && t0 + Tc < 256) {
#pragma unroll
        for (int i = 0; i < M; ++i) {
            size_t r = (size_t)(b0 + i);
            h_ws[r * H + j] = (float)((half_t*)hsmh)[(size_t)i * H + j];
            c_ws[r * H + j] = cst[i];
        }
    }
}

// ---------------------------------------------------------------------------
// Recurrent kernel, fp32 + LDS-persistent U (layers 3-4). XW fp16. M=2.
// ---------------------------------------------------------------------------
template<int H, int M, int G, bool LAST>
__global__ __launch_bounds__(H * G) void lstm_rec32(
    const half_t* __restrict__ XW, const float* __restrict__ Ut,
    const float* __restrict__ bn_g, const float* __restrict__ bn_b,
    const float* __restrict__ bn_m, const float* __restrict__ bn_v,
    half_t* __restrict__ outH, float* __restrict__ outF, size_t oRowStride,
    float* __restrict__ h_ws, float* __restrict__ c_ws, int t0, int Tc)
{
    constexpr int TPB = H * G;
    constexpr int GPG = 4 / G;
    constexpr int NCH = H / 4;
    constexpr int H4  = 4 * H;

    const int tid = threadIdx.x;
    const int j   = tid & (H - 1);
    const int g   = tid / H;
    const int b0  = blockIdx.x * M;
    const int cbase = g * GPG * H + j;

    __shared__ float hsm[M][H];
    __shared__ float zx[G - 1][M][GPG][H];
    __shared__ float Us[4 * H * H];

    for (int i = tid * 4; i < 4 * H * H; i += TPB * 4)
        *(float4*)&Us[i] = *(const float4*)&Ut[i];

    float scale = 0.f, shift = 0.f, cst[M];
    if (g == 0) {
        scale = bn_g[j] * rsqrtf(bn_v[j] + 1e-3f);
        shift = bn_b[j] - bn_m[j] * scale;
        if (t0 == 0) {
#pragma unroll
            for (int i = 0; i < M; ++i) cst[i] = 0.f;
        } else {
#pragma unroll
            for (int i = 0; i < M; ++i) cst[i] = c_ws[(size_t)(b0 + i) * H + j];
        }
    }
    if (t0 == 0) {
        for (int c = tid; c < M * H; c += TPB) ((float*)hsm)[c] = 0.f;
    } else {
        for (int c = tid; c < M * H; c += TPB) {
            int r = c / H, jj = c - r * H;
            ((float*)hsm)[c] = h_ws[(size_t)(b0 + r) * H + jj];
        }
    }
    __syncthreads();

    for (int tl = 0; tl < Tc; ++tl) {
        float xwv[M][GPG];
#pragma unroll
        for (int i = 0; i < M; ++i) {
            const half_t* xp = XW + ((size_t)(b0 + i) * Tc + tl) * H4 + cbase;
#pragma unroll
            for (int q = 0; q < GPG; ++q) xwv[i][q] = (float)xp[(size_t)q * H];
        }

        float zp[M][GPG];
#pragma unroll
        for (int i = 0; i < M; ++i)
#pragma unroll
            for (int q = 0; q < GPG; ++q) zp[i][q] = 0.f;

#pragma unroll
        for (int kc = 0; kc < NCH; ++kc) {
            float4 ub[GPG];
#pragma unroll
            for (int q = 0; q < GPG; ++q)
                ub[q] = *(const float4*)&Us[((size_t)kc * H4 + cbase + q * H) * 4];
#pragma unroll
            for (int i = 0; i < M; ++i) {
                const float4 h4 = *(const float4*)&hsm[i][kc * 4];
#pragma unroll
                for (int q = 0; q < GPG; ++q)
                    zp[i][q] += h4.x * ub[q].x + h4.y * ub[q].y
                              + h4.z * ub[q].z + h4.w * ub[q].w;
            }
        }

#pragma unroll
        for (int i = 0; i < M; ++i)
#pragma unroll
            for (int q = 0; q < GPG; ++q) zp[i][q] += xwv[i][q];

        if (g > 0) {
#pragma unroll
            for (int i = 0; i < M; ++i)
#pragma unroll
                for (int q = 0; q < GPG; ++q) zx[g - 1][i][q][j] = zp[i][q];
        }
        __syncthreads();

        if (g == 0) {
            const int t = t0 + tl;
#pragma unroll
            for (int i = 0; i < M; ++i) {
                float zg[4];
#pragma unroll
                for (int gt = 0; gt < 4; ++gt) {
                    int grp = gt / GPG, q = gt - grp * GPG;
                    zg[gt] = (grp == 0) ? zp[i][q] : zx[grp - 1][i][q][j];
                }
                float ig = fsig(zg[0]);
                float fg = fsig(zg[1]);
                float gg = ftanh(zg[2]);
                float og = fsig(zg[3]);
                cst[i] = fg * cst[i] + ig * gg;
                float hv = og * ftanh(cst[i]);
                hsm[i][j] = hv;
                float v = hv * scale + shift;
                size_t r = (size_t)(b0 + i);
                if constexpr (!LAST) {
                    size_t o = r * oRowStride + (size_t)tl * H + j;
                    outH[o] = (half_t)v;
                } else {
                    if (t == 255) outF[r * H + j] = v;
                }
            }
        }
        __syncthreads();
    }

    if (g == 0 && t0 + Tc < 256) {
#pragma unroll
        for (int i = 0; i < M; ++i) {
            size_t r = (size_t)(b0 + i);
            h_ws[r * H + j] = hsm[i][j];
            c_ws[r * H + j] = cst[i];
        }
    }
}

// ---------------------------------------------------------------------------
extern "C" void kernel_launch(void* const* d_in, const int* in_sizes, int n_in,
                              void* d_out, int out_size, void* d_ws, size_t ws_size,
                              hipStream_t stream)
{
    const float* state = (const float*)d_in[0];
    const float *W[4], *U[4], *bi[4], *g[4], *be[4], *mm[4], *vv[4];
    for (int l = 0; l < 4; ++l) {
        W[l]  = (const float*)d_in[1 + 7 * l + 0];
        U[l]  = (const float*)d_in[1 + 7 * l + 1];
        bi[l] = (const float*)d_in[1 + 7 * l + 2];
        g[l]  = (const float*)d_in[1 + 7 * l + 3];
        be[l] = (const float*)d_in[1 + 7 * l + 4];
        mm[l] = (const float*)d_in[1 + 7 * l + 5];
        vv[l] = (const float*)d_in[1 + 7 * l + 6];
    }
    const int HS[4]  = {256, 128, 64, 32};
    const int FIN[4] = {128, 256, 128, 64};

    // ---- fixed-buffer byte sizes ----------------------------------------
    size_t wB[4], uthB[2], utB[2], hB[4];
    size_t fixed = 0;
    for (int l = 0; l < 4; ++l) { wB[l] = (size_t)FIN[l] * 4 * HS[l] * 2; fixed += 2 * ((wB[l] + 15) & ~15ull); }
    for (int l = 0; l < 2; ++l) { uthB[l] = (size_t)4 * HS[l] * HS[l] * 2; fixed += (uthB[l] + 15) & ~15ull; }
    for (int l = 0; l < 2; ++l) { utB[l] = (size_t)4 * HS[l + 2] * HS[l + 2] * 4; fixed += (utB[l] + 15) & ~15ull; }
    for (int l = 0; l < 4; ++l) { hB[l] = (size_t)512 * HS[l] * 4; fixed += 2 * ((hB[l] + 15) & ~15ull); }
    fixed += 1024;  // alignment slack

    // fp16 xw + fp16 single activations
    auto xwBytes  = [&](size_t tc) { return (size_t)512 * tc * 1024 * 2; };
    auto actBytes = [&](size_t t)  { return (size_t)512 * t * (256 + 128 + 64) * 2; };

    int Tc = 256; bool fullAct = true;
    while (Tc > 8 && fixed + xwBytes(Tc) + actBytes(256) > ws_size) Tc >>= 1;
    if (fixed + xwBytes(Tc) + actBytes(256) > ws_size) {
        fullAct = false; Tc = 32;
        while (Tc > 1 && fixed + xwBytes(Tc) + actBytes(Tc) > ws_size) Tc >>= 1;
    }
    int nc = 256 / Tc;
    size_t Tact = fullAct ? 256 : (size_t)Tc;

    // ---- allocate --------------------------------------------------------
    size_t off = 0;
    auto alloc = [&](size_t bytes) -> char* {
        char* p = (char*)d_ws + off;
        off = (off + bytes + 15) & ~15ull;
        return p;
    };
    half_t* xw = (half_t*)alloc(xwBytes(Tc));
    half_t* act[4];
    act[0] = nullptr;
    for (int l = 1; l < 4; ++l)
        act[l] = (half_t*)alloc((size_t)512 * Tact * FIN[l] * 2);
    float *hb[4], *cb[4];
    for (int l = 0; l < 4; ++l) { hb[l] = (float*)alloc(hB[l]); cb[l] = (float*)alloc(hB[l]); }
    uint4* ut4_1 = (uint4*)alloc(uthB[0]);           // layer-1 packed layout
    uint4* ut4_2 = (uint4*)alloc(uthB[1]);           // layer-2 packed layout
    float* ut[2];
    for (int l = 0; l < 2; ++l) ut[l] = (float*)alloc(utB[l]);
    half_t *whi[4], *wlo[4];
    for (int l = 0; l < 4; ++l) { whi[l] = (half_t*)alloc(wB[l]); wlo[l] = (half_t*)alloc(wB[l]); }

    // ---- one-time prep ---------------------------------------------------
    for (int l = 0; l < 4; ++l) {
        int n = FIN[l] * 4 * HS[l];
        w_split_h<<<dim3((n + 255) / 256), dim3(256), 0, stream>>>(W[l], whi[l], wlo[l], FIN[l], 4 * HS[l]);
    }
    {   // layer-1 packed U (2 cols x 4k per uint4)
        int n = (HS[0] / 4) * (HS[0] * 2);           // NCH * TPB = 32768
        u_pack4<<<dim3((n + 255) / 256), dim3(256), 0, stream>>>(U[0], ut4_1, HS[0]);
    }
    {   // layer-2 packed U (1 col x 8k per uint4)
        int n = (HS[1] / 8) * (HS[1] * 4);           // NC2 * TPB = 8192
        u_pack8<<<dim3((n + 255) / 256), dim3(256), 0, stream>>>(U[1], ut4_2, HS[1]);
    }
    for (int l = 0; l < 2; ++l) {
        int n = HS[l + 2] * 4 * HS[l + 2];
        u_chunk<<<dim3((n + 255) / 256), dim3(256), 0, stream>>>(U[l + 2], ut[l], HS[l + 2], 4 * HS[l + 2]);
    }

    // ---- time-chunk-interleaved layer sweep -----------------------------
    for (int c = 0; c < nc; ++c) {
        int t0 = c * Tc;
        for (int l = 0; l < 4; ++l) {
            int K = FIN[l], N4 = 4 * HS[l];
            dim3 gg((512 * Tc) / 64, N4 / 64);

            if (l == 0) {
                const float* Abase = state + (size_t)t0 * 128;
                gemm_f16<true><<<gg, dim3(256), 0, stream>>>(
                    Abase, nullptr, (size_t)256 * 128,
                    whi[0], wlo[0], bi[0], xw, K, N4, Tc);
            } else {
                size_t aOff = fullAct ? (size_t)t0 * K : 0;
                size_t aStride = fullAct ? (size_t)256 * K : (size_t)Tc * K;
                gemm_f16<false><<<gg, dim3(256), 0, stream>>>(
                    nullptr, act[l] + aOff, aStride,
                    whi[l], wlo[l], bi[l], xw, K, N4, Tc);
            }

            half_t* oH = nullptr;
            size_t oStride = 0;
            if (l < 3) {
                size_t oOff = fullAct ? (size_t)t0 * HS[l] : 0;
                oStride = fullAct ? (size_t)256 * HS[l] : (size_t)Tc * HS[l];
                oH = act[l + 1] + oOff;
            }

            if (l == 0)
                lstm_rec_h<256, 2, 2, 1><<<dim3(256), dim3(512), 0, stream>>>(
                    xw, ut4_1, g[0], be[0], mm[0], vv[0],
                    oH, oStride, hb[0], cb[0], t0, Tc);
            else if (l == 1)
                lstm_rec_h<128, 2, 4, 2><<<dim3(256), dim3(512), 0, stream>>>(
                    xw, ut4_2, g[1], be[1], mm[1], vv[1],
                    oH, oStride, hb[1], cb[1], t0, Tc);
            else if (l == 2)
                lstm_rec32<64, 2, 4, false><<<dim3(256), dim3(256), 0, stream>>>(
                    xw, ut[0], g[2], be[2], mm[2], vv[2],
                    oH, nullptr, oStride, hb[2], cb[2], t0, Tc);
            else
                lstm_rec32<32, 2, 4, true><<<dim3(256), dim3(128), 0, stream>>>(
                    xw, ut[1], g[3], be[3], mm[3], vv[3],
                    nullptr, (float*)d_out, 0, hb[3], cb[3], t0, Tc);
        }
    }
}